// Round 1
// baseline (442.365 us; speedup 1.0000x reference)
//
#include <hip/hip_runtime.h>
#include <math.h>

#define NANG 120
#define NB   16
#define H    50
#define SD   100
#define NBIN 51        // rfft bins of length-100
#define PADB 3         // top pad rows of B-hat
#define BROWS 60       // stored rows: r in [-3, 56]
#define BST  104       // B-hat row stride (2*51=102 -> pad 104)
#define RTST 52        // Rt row stride
#define CST  56        // C lag-dim stride (<=52 lags -> pad 56)

// ---- device-global scratch (avoids ws_size assumptions) ----
__device__ __align__(16) float g_Arec[NB*2*H*NBIN*2 + 64]; // [b][c][x][om][2]
__device__ __align__(16) float g_ligc[NB*2*H*H];           // [b][c][y][x]
__device__ __align__(16) float g_W[H*BST];                 // [y][2*om+p] = (cos, -sin)
__device__ __align__(16) float g_CT[NBIN*SD + 64];         // [om][d] cos(2*pi*om*dy'/100)
__device__ __align__(16) float g_ST[NBIN*SD + 64];
__device__ float g_resV[NANG*NB];
__device__ int   g_resP[NANG*NB];

// ================= prep: conv+relu+combine, rec spectrum, tables =================
__global__ __launch_bounds__(256) void k_prep(const float* __restrict__ rec,
                                              const float* __restrict__ lig,
                                              const float* __restrict__ wr,
                                              const float* __restrict__ br,
                                              const float* __restrict__ wsc) {
  const int blk = blockIdx.x;
  const int tid = threadIdx.x;
  if (blk == NB) {
    // W table (y-DFT twiddles) + inverse tables CT/ST
    for (int u = tid; u < H*BST; u += 256) {
      int y = u / BST, col = u % BST;
      float v = 0.f;
      if (col < 2*NBIN) {
        int om = col >> 1;
        int k = (om * y) % SD;
        double ang = 6.283185307179586 * (double)k / 100.0;
        v = (col & 1) ? (float)(-sin(ang)) : (float)cos(ang);
      }
      g_W[u] = v;
    }
    for (int u = tid; u < NBIN*SD; u += 256) {
      int om = u / SD, d = u % SD;
      int dy = d - 49;                 // d in 0..98 used
      int dyp = (dy + 100) % 100;
      int k = (om * dyp) % SD;
      double ang = 6.283185307179586 * (double)k / 100.0;
      g_CT[u] = (float)cos(ang);
      g_ST[u] = (float)sin(ang);
    }
    return;
  }
  const int b = blk;
  __shared__ float recf[2*H*H];
  __shared__ float tbl[SD*2];
  for (int k = tid; k < SD; k += 256) {
    double ang = 6.283185307179586 * (double)k / 100.0;
    tbl[2*k]   = (float)cos(ang);
    tbl[2*k+1] = (float)sin(ang);
  }
  const float* rimg = rec + b*H*H;
  const float* limg = lig + b*H*H;
  for (int p = tid; p < H*H; p += 256) {
    int i = p / H, j = p - (p/H)*H;
    float ar0 = br[0], ar1 = br[1], al0 = br[0], al1 = br[1];
    for (int di = 0; di < 3; ++di) {
      int ii = i + di - 1;
      if (ii < 0 || ii >= H) continue;
      for (int dj = 0; dj < 3; ++dj) {
        int jj = j + dj - 1;
        if (jj < 0 || jj >= H) continue;
        float rv = rimg[ii*H+jj], lv = limg[ii*H+jj];
        float w0 = wr[di*3 + dj], w1 = wr[9 + di*3 + dj];
        ar0 += w0*rv; ar1 += w1*rv; al0 += w0*lv; al1 += w1*lv;
      }
    }
    ar0 = fmaxf(ar0, 0.f); ar1 = fmaxf(ar1, 0.f);
    al0 = fmaxf(al0, 0.f); al1 = fmaxf(al1, 0.f);
    recf[p] = ar0; recf[H*H + p] = ar1;
    g_ligc[((b*2+0)*H + i)*H + j] = wsc[0]*al0 + wsc[1]*al1;
    g_ligc[((b*2+1)*H + i)*H + j] = wsc[2]*al0 + wsc[3]*al1;
  }
  __syncthreads();
  // row-DFT of rec features -> g_Arec (conj applied later in stage-2 formula)
  for (int u = tid; u < 2*H*NBIN; u += 256) {
    int om = u % NBIN; int rest = u / NBIN; int x = rest % H; int c = rest / H;
    const float* row = recf + (c*H + x)*H;
    float sr = 0.f, si = 0.f;
    int k = 0;
    for (int y = 0; y < H; ++y) {
      float rv = row[y];
      sr += rv * tbl[2*k];
      si -= rv * tbl[2*k+1];
      k += om; if (k >= SD) k -= SD;
    }
    float* dst = g_Arec + (((b*2+c)*H + x)*NBIN + om)*2;
    dst[0] = sr; dst[1] = si;
  }
}

// ================= main: per (angle,batch) block =================
__global__ __launch_bounds__(256) void k_main() {
  const int bid = blockIdx.x;
  const int a = bid % NANG;
  const int b = bid / NANG;
  const int tid = threadIdx.x;

  __shared__ __align__(16) float sB[2*BROWS*BST];   // B-hat: [c][row][2*om+p]
  __shared__ __align__(16) float sRC[2*NBIN*CST];   // union: Rt (5200f) then Cr|Ci
  __shared__ float sRedV[256];
  __shared__ int   sRedP[256];
  float* Rt = sRC;                    // [c][j][i], stride RTST
  float* Cr = sRC;                    // [om][lagIdx]
  float* Ci = sRC + NBIN*CST;

  // P0: zero-fill pad rows of sB
  for (int u = tid; u < 2*BROWS*BST; u += 256) {
    int row = (u / BST) % BROWS;
    if (row < PADB || row >= PADB + H) sB[u] = 0.f;
  }

  // P1: bilinear rotation of combined ligand features -> Rt (transposed)
  float angf = 0.05235987755982988f * (float)a;
  float ca = cosf(angf), sa = sinf(angf);
  const float* L0 = g_ligc + (b*2+0)*H*H;
  const float* L1 = g_ligc + (b*2+1)*H*H;
  for (int p = tid; p < H*H; p += 256) {
    int i = p / H, j = p - (p/H)*H;
    float gy = -1.f + (float)i*(2.f/49.f);
    float gx = -1.f + (float)j*(2.f/49.f);
    float x_in = ca*gx - sa*gy;
    float y_in = sa*gx + ca*gy;
    float px = (x_in + 1.f)*0.5f*49.f;
    float py = (y_in + 1.f)*0.5f*49.f;
    float fx = floorf(px), fy = floorf(py);
    int x0 = (int)fx, y0 = (int)fy;
    int x1 = x0 + 1, y1 = y0 + 1;
    float wx1 = px - fx, wx0 = 1.f - wx1;
    float wy1 = py - fy, wy0 = 1.f - wy1;
    float v0 = 0.f, v1 = 0.f;
    if (y0 >= 0 && y0 < H) {
      if (x0 >= 0 && x0 < H) { float w = wy0*wx0; int o = y0*H+x0; v0 += w*L0[o]; v1 += w*L1[o]; }
      if (x1 >= 0 && x1 < H) { float w = wy0*wx1; int o = y0*H+x1; v0 += w*L0[o]; v1 += w*L1[o]; }
    }
    if (y1 >= 0 && y1 < H) {
      if (x0 >= 0 && x0 < H) { float w = wy1*wx0; int o = y1*H+x0; v0 += w*L0[o]; v1 += w*L1[o]; }
      if (x1 >= 0 && x1 < H) { float w = wy1*wx1; int o = y1*H+x1; v0 += w*L0[o]; v1 += w*L1[o]; }
    }
    Rt[(0*H + j)*RTST + i] = v0;
    Rt[(1*H + j)*RTST + i] = v1;
  }
  __syncthreads();

  // P2: y-DFT of rotated image rows -> sB (interior rows)
  for (int u = tid; u < 2*13*13; u += 256) {
    int cg = u % 13;
    int rest = u / 13;
    int it = rest % 13;
    int c = rest / 13;
    int i0 = it*4, col0 = cg*8;
    float acc[4][8];
    #pragma unroll
    for (int r = 0; r < 4; ++r)
      #pragma unroll
      for (int q = 0; q < 8; ++q) acc[r][q] = 0.f;
    const float* rtc = Rt + c*H*RTST + i0;
    const float* wt = g_W + col0;
    #pragma unroll 2
    for (int y = 0; y < H; ++y) {
      float4 rv = *(const float4*)&rtc[y*RTST];
      float4 w0 = *(const float4*)&wt[y*BST];
      float4 w1 = *(const float4*)&wt[y*BST + 4];
      float rr[4] = {rv.x, rv.y, rv.z, rv.w};
      float ww[8] = {w0.x, w0.y, w0.z, w0.w, w1.x, w1.y, w1.z, w1.w};
      #pragma unroll
      for (int r = 0; r < 4; ++r)
        #pragma unroll
        for (int q = 0; q < 8; ++q) acc[r][q] += rr[r]*ww[q];
    }
    float* dst = sB + c*BROWS*BST + col0;
    #pragma unroll
    for (int r = 0; r < 4; ++r) {
      int i = i0 + r;
      if (i < H) {
        float4 o0 = {acc[r][0], acc[r][1], acc[r][2], acc[r][3]};
        float4 o1 = {acc[r][4], acc[r][5], acc[r][6], acc[r][7]};
        *(float4*)&dst[(PADB + i)*BST] = o0;
        *(float4*)&dst[(PADB + i)*BST + 4] = o1;
      }
    }
  }
  __syncthreads();

  float bestV = 3.0e38f; int bestP = 0;
  const int wid = tid >> 6, lane = tid & 63;
  const int om = (lane <= 50) ? lane : 50;
  const bool omValid = (lane <= 50);

  for (int h = 0; h < 2; ++h) {
    const int lagBase = h ? -1 : -49;
    const int ntiles = h ? 13 : 12;

    // P3: per-bin complex correlation along x -> C[om][lag]
    for (int t = wid; t < ntiles; t += 4) {
      int d0 = lagBase + 4*t;
      int x_lo = max(0, -(d0+3));
      int x_hi = min(H, H - d0);
      float cr0=0,cr1=0,cr2=0,cr3=0, ci0=0,ci1=0,ci2=0,ci3=0;
      #pragma unroll 1
      for (int c = 0; c < 2; ++c) {
        const float* Ab = g_Arec + ((b*2 + c)*H*NBIN)*2 + 2*om;
        const float* Bb = sB + c*BROWS*BST + 2*om;
        float br_[8], bi_[8], ar_[8], ai_[8];
        #pragma unroll
        for (int s = 0; s < 8; ++s) {
          int r = min(x_lo + d0 + s, 56);
          float2 bv = *(const float2*)&Bb[(PADB + r)*BST];
          br_[s] = bv.x; bi_[s] = bv.y;
          int xx = x_lo + s;
          float2 av = *(const float2*)&Ab[min(xx, H-1)*NBIN*2];
          bool ok = xx < x_hi;
          ar_[s] = ok ? av.x : 0.f; ai_[s] = ok ? av.y : 0.f;
        }
        int ng = (x_hi - x_lo + 7) >> 3;
        int xb = x_lo;
        for (int g = 0; g < ng; ++g) {
          #pragma unroll
          for (int u = 0; u < 8; ++u) {
            float Ar = ar_[u], Ai = ai_[u];
            { int sl = u;       cr0 += Ar*br_[sl] + Ai*bi_[sl]; ci0 += Ar*bi_[sl] - Ai*br_[sl]; }
            { int sl = (u+1)&7; cr1 += Ar*br_[sl] + Ai*bi_[sl]; ci1 += Ar*bi_[sl] - Ai*br_[sl]; }
            { int sl = (u+2)&7; cr2 += Ar*br_[sl] + Ai*bi_[sl]; ci2 += Ar*bi_[sl] - Ai*br_[sl]; }
            { int sl = (u+3)&7; cr3 += Ar*br_[sl] + Ai*bi_[sl]; ci3 += Ar*bi_[sl] - Ai*br_[sl]; }
            int rn = min(xb + u + 8 + d0, 56);
            float2 bv = *(const float2*)&Bb[(PADB + rn)*BST];
            br_[u] = bv.x; bi_[u] = bv.y;
            int xx = xb + u + 8;
            float2 av = *(const float2*)&Ab[min(xx, H-1)*NBIN*2];
            bool ok = xx < x_hi;
            ar_[u] = ok ? av.x : 0.f; ai_[u] = ok ? av.y : 0.f;
          }
          xb += 8;
        }
      }
      if (om == 0 || om == 50) {
        cr0*=0.5f; cr1*=0.5f; cr2*=0.5f; cr3*=0.5f;
        ci0*=0.5f; ci1*=0.5f; ci2*=0.5f; ci3*=0.5f;
      }
      if (omValid) {
        float4 c4 = {cr0, cr1, cr2, cr3};
        float4 i4 = {ci0, ci1, ci2, ci3};
        *(float4*)&Cr[om*CST + 4*t] = c4;
        *(float4*)&Ci[om*CST + 4*t] = i4;
      }
    }
    __syncthreads();

    // P4: inverse DFT along omega + local min tracking
    {
      int units = ntiles * 13;
      if (tid < units) {
        int lt = tid % ntiles;
        int dt = tid / ntiles;
        int l0 = 4*lt, dB = 8*dt;
        float s[4][8];
        #pragma unroll
        for (int k = 0; k < 4; ++k)
          #pragma unroll
          for (int j = 0; j < 8; ++j) s[k][j] = 0.f;
        const float* crp = Cr + l0;
        const float* cip = Ci + l0;
        const float* ctp = g_CT + dB;
        const float* stp = g_ST + dB;
        #pragma unroll 2
        for (int om2 = 0; om2 < NBIN; ++om2) {
          float4 c4 = *(const float4*)&crp[om2*CST];
          float4 i4 = *(const float4*)&cip[om2*CST];
          float4 t0 = *(const float4*)&ctp[om2*SD];
          float4 t1 = *(const float4*)&ctp[om2*SD + 4];
          float4 s0 = *(const float4*)&stp[om2*SD];
          float4 s1 = *(const float4*)&stp[om2*SD + 4];
          float cc[4] = {c4.x,c4.y,c4.z,c4.w};
          float ii[4] = {i4.x,i4.y,i4.z,i4.w};
          float ct[8] = {t0.x,t0.y,t0.z,t0.w,t1.x,t1.y,t1.z,t1.w};
          float st[8] = {s0.x,s0.y,s0.z,s0.w,s1.x,s1.y,s1.z,s1.w};
          #pragma unroll
          for (int k = 0; k < 4; ++k)
            #pragma unroll
            for (int j = 0; j < 8; ++j)
              s[k][j] += cc[k]*ct[j] - ii[k]*st[j];
        }
        #pragma unroll
        for (int k = 0; k < 4; ++k) {
          int lag = lagBase + l0 + k;
          #pragma unroll
          for (int j = 0; j < 8; ++j) {
            int d = dB + j;
            if (lag <= 49 && d <= 98) {
              float v = s[k][j];
              int pos = (lag + 50)*SD + (d + 1);
              if (v < bestV || (v == bestV && pos < bestP)) { bestV = v; bestP = pos; }
            }
          }
        }
      }
    }
    __syncthreads();
  }

  // block min-reduce (lexicographic (val, pos))
  sRedV[tid] = bestV; sRedP[tid] = bestP;
  __syncthreads();
  for (int off = 128; off > 0; off >>= 1) {
    if (tid < off) {
      float v2 = sRedV[tid+off]; int p2 = sRedP[tid+off];
      if (v2 < sRedV[tid] || (v2 == sRedV[tid] && p2 < sRedP[tid])) {
        sRedV[tid] = v2; sRedP[tid] = p2;
      }
    }
    __syncthreads();
  }
  if (tid == 0) { g_resV[bid] = sRedV[0]; g_resP[bid] = sRedP[0]; }
}

// ================= final: reduce over angles, emit outputs =================
__global__ void k_final(float* __restrict__ out) {
  int b = threadIdx.x;
  if (b >= NB) return;
  // seed replicates "all scores >= 0 -> border zero at a=0, pos=0"
  float bv = 0.f; int bp = 0; int ba = 0;
  for (int a = 0; a < NANG; ++a) {
    float v = g_resV[b*NANG + a];
    if (v < bv) { bv = v; bp = g_resP[b*NANG + a]; ba = a; }
  }
  out[b] = 0.05235987755982988f * (float)ba;
  out[NB + 2*b]     = (float)(bp / SD) - 50.f;
  out[NB + 2*b + 1] = (float)(bp % SD) - 50.f;
}

extern "C" void kernel_launch(void* const* d_in, const int* in_sizes, int n_in,
                              void* d_out, int out_size, void* d_ws, size_t ws_size,
                              hipStream_t stream) {
  const float* rec = (const float*)d_in[0];
  const float* lig = (const float*)d_in[1];
  const float* wr  = (const float*)d_in[2];
  const float* br  = (const float*)d_in[3];
  const float* wsc = (const float*)d_in[4];
  (void)in_sizes; (void)n_in; (void)out_size; (void)d_ws; (void)ws_size;
  hipLaunchKernelGGL(k_prep, dim3(NB+1), dim3(256), 0, stream, rec, lig, wr, br, wsc);
  hipLaunchKernelGGL(k_main, dim3(NANG*NB), dim3(256), 0, stream);
  hipLaunchKernelGGL(k_final, dim3(1), dim3(64), 0, stream, (float*)d_out);
}

// Round 2
// 385.946 us; speedup vs baseline: 1.1462x; 1.1462x over previous
//
#include <hip/hip_runtime.h>
#include <math.h>

#define NANG 120
#define NB   16
#define H    50
#define SD   100
#define NBIN 51        // rfft bins of length-100
#define PADB 3         // top pad rows of B-hat
#define BROWS 60       // stored rows: r in [-3, 56]
#define BST  104       // B-hat row stride (2*51=102 -> pad 104)
#define RTST 52        // Rt row stride
#define CST  56        // C lag-dim stride (<=52 lags -> pad 56)
#define TST  208       // g_CST row stride in floats (104 d-slots * 2)

// ---- device-global scratch ----
__device__ __align__(16) float g_Arec[NB*2*H*NBIN*2 + 64]; // [b][c][x][om][2]
__device__ __align__(16) float g_ligc[NB*2*H*H];           // [b][c][y][x]
__device__ __align__(16) float g_W[H*BST];                 // [y][2*om+p] = (cos, -sin)
__device__ __align__(16) float g_CST[NBIN*TST + 64];       // [om][d][2] = (cos, sin)
__device__ float g_resV[NANG*NB];
__device__ int   g_resP[NANG*NB];

// cost-balanced tile->wave schedule for P3 (padded x-lens 8..56)
__device__ const int g_sched[2][4][4] = {
  {{0,11,4,-1},{1,10,5,-1},{2,9,6,-1},{3,8,7,-1}},   // h=0: 80/80/88/88
  {{0,5,12,-1},{1,4,10,-1},{2,3,11,-1},{6,7,8,9}}    // h=1: 96/104/96/96
};

// ================= prep: conv+relu+combine, rec spectrum, tables =================
__global__ __launch_bounds__(256) void k_prep(const float* __restrict__ rec,
                                              const float* __restrict__ lig,
                                              const float* __restrict__ wr,
                                              const float* __restrict__ br,
                                              const float* __restrict__ wsc) {
  const int blk = blockIdx.x;
  const int tid = threadIdx.x;
  if (blk == NB) {
    // W table (y-DFT twiddles)
    for (int u = tid; u < H*BST; u += 256) {
      int y = u / BST, col = u % BST;
      float v = 0.f;
      if (col < 2*NBIN) {
        int om = col >> 1;
        int k = (om * y) % SD;
        double ang = 6.283185307179586 * (double)k / 100.0;
        v = (col & 1) ? (float)(-sin(ang)) : (float)cos(ang);
      }
      g_W[u] = v;
    }
    // merged inverse table: (cos, sin) interleaved, d in 0..101
    for (int u = tid; u < NBIN*104; u += 256) {
      int om = u / 104, d = u % 104;
      if (d < 102) {
        int dy = d - 49;
        int dyp = (dy + 100) % 100;
        int k = (om * dyp) % SD;
        double ang = 6.283185307179586 * (double)k / 100.0;
        g_CST[om*TST + 2*d]     = (float)cos(ang);
        g_CST[om*TST + 2*d + 1] = (float)sin(ang);
      }
    }
    return;
  }
  const int b = blk;
  __shared__ float recf[2*H*H];
  __shared__ float tbl[SD*2];
  for (int k = tid; k < SD; k += 256) {
    double ang = 6.283185307179586 * (double)k / 100.0;
    tbl[2*k]   = (float)cos(ang);
    tbl[2*k+1] = (float)sin(ang);
  }
  const float* rimg = rec + b*H*H;
  const float* limg = lig + b*H*H;
  for (int p = tid; p < H*H; p += 256) {
    int i = p / H, j = p - (p/H)*H;
    float ar0 = br[0], ar1 = br[1], al0 = br[0], al1 = br[1];
    for (int di = 0; di < 3; ++di) {
      int ii = i + di - 1;
      if (ii < 0 || ii >= H) continue;
      for (int dj = 0; dj < 3; ++dj) {
        int jj = j + dj - 1;
        if (jj < 0 || jj >= H) continue;
        float rv = rimg[ii*H+jj], lv = limg[ii*H+jj];
        float w0 = wr[di*3 + dj], w1 = wr[9 + di*3 + dj];
        ar0 += w0*rv; ar1 += w1*rv; al0 += w0*lv; al1 += w1*lv;
      }
    }
    ar0 = fmaxf(ar0, 0.f); ar1 = fmaxf(ar1, 0.f);
    al0 = fmaxf(al0, 0.f); al1 = fmaxf(al1, 0.f);
    recf[p] = ar0; recf[H*H + p] = ar1;
    g_ligc[((b*2+0)*H + i)*H + j] = wsc[0]*al0 + wsc[1]*al1;
    g_ligc[((b*2+1)*H + i)*H + j] = wsc[2]*al0 + wsc[3]*al1;
  }
  __syncthreads();
  // row-DFT of rec features -> g_Arec
  for (int u = tid; u < 2*H*NBIN; u += 256) {
    int om = u % NBIN; int rest = u / NBIN; int x = rest % H; int c = rest / H;
    const float* row = recf + (c*H + x)*H;
    float sr = 0.f, si = 0.f;
    int k = 0;
    for (int y = 0; y < H; ++y) {
      float rv = row[y];
      sr += rv * tbl[2*k];
      si -= rv * tbl[2*k+1];
      k += om; if (k >= SD) k -= SD;
    }
    float* dst = g_Arec + (((b*2+c)*H + x)*NBIN + om)*2;
    dst[0] = sr; dst[1] = si;
  }
}

// ================= main: per (angle,batch) block =================
__global__ __launch_bounds__(256) void k_main() {
  const int bid = blockIdx.x;
  const int a = bid % NANG;
  const int b = bid / NANG;
  const int tid = threadIdx.x;

  __shared__ __align__(16) float sB[2*BROWS*BST];   // B-hat: [c][row][2*om+p]
  __shared__ __align__(16) float sRC[2*NBIN*CST];   // union: Rt (5200f) then Cr|Ci
  __shared__ float sRedV[256];
  __shared__ int   sRedP[256];
  float* Rt = sRC;                    // [c][j][i], stride RTST
  float* Cr = sRC;                    // [om][lagIdx]
  float* Ci = sRC + NBIN*CST;

  // P0: zero-fill pad rows of sB
  for (int u = tid; u < 2*BROWS*BST; u += 256) {
    int row = (u / BST) % BROWS;
    if (row < PADB || row >= PADB + H) sB[u] = 0.f;
  }

  // P1: bilinear rotation of combined ligand features -> Rt (transposed)
  float angf = 0.05235987755982988f * (float)a;
  float ca = cosf(angf), sa = sinf(angf);
  const float* L0 = g_ligc + (b*2+0)*H*H;
  const float* L1 = g_ligc + (b*2+1)*H*H;
  for (int p = tid; p < H*H; p += 256) {
    int i = p / H, j = p - (p/H)*H;
    float gy = -1.f + (float)i*(2.f/49.f);
    float gx = -1.f + (float)j*(2.f/49.f);
    float x_in = ca*gx - sa*gy;
    float y_in = sa*gx + ca*gy;
    float px = (x_in + 1.f)*0.5f*49.f;
    float py = (y_in + 1.f)*0.5f*49.f;
    float fx = floorf(px), fy = floorf(py);
    int x0 = (int)fx, y0 = (int)fy;
    int x1 = x0 + 1, y1 = y0 + 1;
    float wx1 = px - fx, wx0 = 1.f - wx1;
    float wy1 = py - fy, wy0 = 1.f - wy1;
    float v0 = 0.f, v1 = 0.f;
    if (y0 >= 0 && y0 < H) {
      if (x0 >= 0 && x0 < H) { float w = wy0*wx0; int o = y0*H+x0; v0 += w*L0[o]; v1 += w*L1[o]; }
      if (x1 >= 0 && x1 < H) { float w = wy0*wx1; int o = y0*H+x1; v0 += w*L0[o]; v1 += w*L1[o]; }
    }
    if (y1 >= 0 && y1 < H) {
      if (x0 >= 0 && x0 < H) { float w = wy1*wx0; int o = y1*H+x0; v0 += w*L0[o]; v1 += w*L1[o]; }
      if (x1 >= 0 && x1 < H) { float w = wy1*wx1; int o = y1*H+x1; v0 += w*L0[o]; v1 += w*L1[o]; }
    }
    Rt[(0*H + j)*RTST + i] = v0;
    Rt[(1*H + j)*RTST + i] = v1;
  }
  __syncthreads();

  // P2: y-DFT of rotated image rows -> sB (tiles of 4 rows x 12 cols, 234 units)
  if (tid < 234) {
    int c = tid / 117;            // 13*9
    int r = tid % 117;
    int it = r % 13;
    int cg = r / 13;
    int i0 = it*4;
    int col0 = (cg == 8) ? 90 : 12*cg;   // last tile overlaps (benign identical writes)
    float acc[4][12];
    #pragma unroll
    for (int p = 0; p < 4; ++p)
      #pragma unroll
      for (int q = 0; q < 12; ++q) acc[p][q] = 0.f;
    const float* rtc = Rt + c*H*RTST + i0;
    const float* wt = g_W + col0;
    #pragma unroll 2
    for (int y = 0; y < H; ++y) {
      float4 rv = *(const float4*)&rtc[y*RTST];
      float ww[12];
      #pragma unroll
      for (int q = 0; q < 6; ++q) {
        float2 w2 = *(const float2*)&wt[y*BST + 2*q];
        ww[2*q] = w2.x; ww[2*q+1] = w2.y;
      }
      float rr[4] = {rv.x, rv.y, rv.z, rv.w};
      #pragma unroll
      for (int p = 0; p < 4; ++p)
        #pragma unroll
        for (int q = 0; q < 12; ++q) acc[p][q] += rr[p]*ww[q];
    }
    float* dst = sB + c*BROWS*BST + col0;
    #pragma unroll
    for (int p = 0; p < 4; ++p) {
      int i = i0 + p;
      if (i < H) {
        #pragma unroll
        for (int q = 0; q < 6; ++q) {
          float2 o = {acc[p][2*q], acc[p][2*q+1]};
          *(float2*)&dst[(PADB+i)*BST + 2*q] = o;
        }
      }
    }
  }
  __syncthreads();

  float bestV = 3.0e38f; int bestP = 0;
  const int wid = tid >> 6, lane = tid & 63;
  const int om = (lane <= 50) ? lane : 50;
  const bool omValid = (lane <= 50);

  for (int h = 0; h < 2; ++h) {
    const int lagBase = h ? -1 : -49;

    // P3: per-bin complex correlation along x -> C[om][lag] (balanced schedule)
    for (int ti = 0; ti < 4; ++ti) {
      int t = g_sched[h][wid][ti];
      if (t < 0) break;
      int d0 = lagBase + 4*t;
      int x_lo = max(0, -(d0+3));
      int x_hi = min(H, H - d0);
      float cr0=0,cr1=0,cr2=0,cr3=0, ci0=0,ci1=0,ci2=0,ci3=0;
      #pragma unroll 1
      for (int c = 0; c < 2; ++c) {
        const float* Ab = g_Arec + ((b*2 + c)*H*NBIN)*2 + 2*om;
        const float* Bb = sB + c*BROWS*BST + 2*om;
        float br_[8], bi_[8], ar_[8], ai_[8];
        #pragma unroll
        for (int s = 0; s < 8; ++s) {
          int r = min(x_lo + d0 + s, 56);
          float2 bv = *(const float2*)&Bb[(PADB + r)*BST];
          br_[s] = bv.x; bi_[s] = bv.y;
          int xx = x_lo + s;
          float2 av = *(const float2*)&Ab[min(xx, H-1)*NBIN*2];
          bool ok = xx < x_hi;
          ar_[s] = ok ? av.x : 0.f; ai_[s] = ok ? av.y : 0.f;
        }
        int ng = (x_hi - x_lo + 7) >> 3;
        int xb = x_lo;
        for (int g = 0; g < ng; ++g) {
          #pragma unroll
          for (int u = 0; u < 8; ++u) {
            float Ar = ar_[u], Ai = ai_[u];
            { int sl = u;       cr0 += Ar*br_[sl] + Ai*bi_[sl]; ci0 += Ar*bi_[sl] - Ai*br_[sl]; }
            { int sl = (u+1)&7; cr1 += Ar*br_[sl] + Ai*bi_[sl]; ci1 += Ar*bi_[sl] - Ai*br_[sl]; }
            { int sl = (u+2)&7; cr2 += Ar*br_[sl] + Ai*bi_[sl]; ci2 += Ar*bi_[sl] - Ai*br_[sl]; }
            { int sl = (u+3)&7; cr3 += Ar*br_[sl] + Ai*bi_[sl]; ci3 += Ar*bi_[sl] - Ai*br_[sl]; }
            int rn = min(xb + u + 8 + d0, 56);
            float2 bv = *(const float2*)&Bb[(PADB + rn)*BST];
            br_[u] = bv.x; bi_[u] = bv.y;
            int xx = xb + u + 8;
            float2 av = *(const float2*)&Ab[min(xx, H-1)*NBIN*2];
            bool ok = xx < x_hi;
            ar_[u] = ok ? av.x : 0.f; ai_[u] = ok ? av.y : 0.f;
          }
          xb += 8;
        }
      }
      if (om == 0 || om == 50) {
        cr0*=0.5f; cr1*=0.5f; cr2*=0.5f; cr3*=0.5f;
        ci0*=0.5f; ci1*=0.5f; ci2*=0.5f; ci3*=0.5f;
      }
      if (omValid) {
        float4 c4 = {cr0, cr1, cr2, cr3};
        float4 i4 = {ci0, ci1, ci2, ci3};
        *(float4*)&Cr[om*CST + 4*t] = c4;
        *(float4*)&Ci[om*CST + 4*t] = i4;
      }
    }
    __syncthreads();

    // P4: inverse DFT along omega + local min tracking (tiles 4 lag x 6 d)
    {
      const int nLT = h ? 13 : 12;
      const int units = nLT * 17;
      if (tid < units) {
        int lt = tid % nLT;
        int dt = tid / nLT;
        int l0 = 4*lt, d0 = 6*dt;
        float s[4][6];
        #pragma unroll
        for (int k = 0; k < 4; ++k)
          #pragma unroll
          for (int j = 0; j < 6; ++j) s[k][j] = 0.f;
        const float* crp = Cr + l0;
        const float* cip = Ci + l0;
        const float* tp = g_CST + d0*2;
        #pragma unroll 3
        for (int om2 = 0; om2 < NBIN; ++om2) {
          float4 c4 = *(const float4*)&crp[om2*CST];
          float4 i4 = *(const float4*)&cip[om2*CST];
          float4 t0 = *(const float4*)&tp[om2*TST];
          float4 t1 = *(const float4*)&tp[om2*TST + 4];
          float4 t2 = *(const float4*)&tp[om2*TST + 8];
          float cc[4] = {c4.x,c4.y,c4.z,c4.w};
          float ii[4] = {i4.x,i4.y,i4.z,i4.w};
          float tt[12] = {t0.x,t0.y,t0.z,t0.w,t1.x,t1.y,t1.z,t1.w,t2.x,t2.y,t2.z,t2.w};
          #pragma unroll
          for (int k = 0; k < 4; ++k)
            #pragma unroll
            for (int j = 0; j < 6; ++j)
              s[k][j] += cc[k]*tt[2*j] - ii[k]*tt[2*j+1];
        }
        #pragma unroll
        for (int k = 0; k < 4; ++k) {
          int lag = lagBase + l0 + k;
          if (lag <= 49) {
            #pragma unroll
            for (int j = 0; j < 6; ++j) {
              int d = d0 + j;
              if (d <= 98) {
                float v = s[k][j];
                int pos = (lag + 50)*SD + (d + 1);
                if (v < bestV || (v == bestV && pos < bestP)) { bestV = v; bestP = pos; }
              }
            }
          }
        }
      }
    }
    __syncthreads();
  }

  // block min-reduce (lexicographic (val, pos))
  sRedV[tid] = bestV; sRedP[tid] = bestP;
  __syncthreads();
  for (int off = 128; off > 0; off >>= 1) {
    if (tid < off) {
      float v2 = sRedV[tid+off]; int p2 = sRedP[tid+off];
      if (v2 < sRedV[tid] || (v2 == sRedV[tid] && p2 < sRedP[tid])) {
        sRedV[tid] = v2; sRedP[tid] = p2;
      }
    }
    __syncthreads();
  }
  if (tid == 0) { g_resV[bid] = sRedV[0]; g_resP[bid] = sRedP[0]; }
}

// ================= final: reduce over angles, emit outputs =================
__global__ void k_final(float* __restrict__ out) {
  int b = threadIdx.x;
  if (b >= NB) return;
  float bv = 0.f; int bp = 0; int ba = 0;
  for (int a = 0; a < NANG; ++a) {
    float v = g_resV[b*NANG + a];
    if (v < bv) { bv = v; bp = g_resP[b*NANG + a]; ba = a; }
  }
  out[b] = 0.05235987755982988f * (float)ba;
  out[NB + 2*b]     = (float)(bp / SD) - 50.f;
  out[NB + 2*b + 1] = (float)(bp % SD) - 50.f;
}

extern "C" void kernel_launch(void* const* d_in, const int* in_sizes, int n_in,
                              void* d_out, int out_size, void* d_ws, size_t ws_size,
                              hipStream_t stream) {
  const float* rec = (const float*)d_in[0];
  const float* lig = (const float*)d_in[1];
  const float* wr  = (const float*)d_in[2];
  const float* br  = (const float*)d_in[3];
  const float* wsc = (const float*)d_in[4];
  (void)in_sizes; (void)n_in; (void)out_size; (void)d_ws; (void)ws_size;
  hipLaunchKernelGGL(k_prep, dim3(NB+1), dim3(256), 0, stream, rec, lig, wr, br, wsc);
  hipLaunchKernelGGL(k_main, dim3(NANG*NB), dim3(256), 0, stream);
  hipLaunchKernelGGL(k_final, dim3(1), dim3(64), 0, stream, (float*)d_out);
}

// Round 3
// 369.880 us; speedup vs baseline: 1.1960x; 1.0434x over previous
//
#include <hip/hip_runtime.h>
#include <math.h>

#define NANG 120
#define NB   16
#define H    50
#define SD   100
#define NBIN 51        // rfft bins of length-100
#define PADB 3         // top pad rows of B-hat
#define BROWS 60       // stored rows: r in [-3, 56]
#define BST  106       // B-hat row stride (non mult-of-32-words: fewer bank conflicts)
#define WST  104       // g_W row stride
#define RTST 52        // Rt row stride
#define CST  58        // C lag-dim stride (58%32=26 -> store conflicts ~3-way)
#define AX   58        // g_Arec x rows (50 real + 8 zero pad)

// ---- device-global scratch ----
__device__ __align__(16) float g_Arec[NB*2*AX*NBIN*2 + 64]; // [b][c][x][om][2], x 50..57 zero
__device__ __align__(16) float g_ligc[NB*2*H*H];            // [b][c][y][x]
__device__ __align__(16) float g_W[H*WST];                  // [y][2*om+p] = (cos, -sin)
__device__ __align__(16) float g_P[NBIN*128 + 64];          // [om][2*dy+p] = (cos,sin), dy 0..49, else 0
__device__ float g_resV[NANG*NB];
__device__ int   g_resP[NANG*NB];

// cost-balanced tile->wave schedule for P3 (unit = ceil(len/8))
__device__ const int g_sched[2][4][4] = {
  {{0,11,4,-1},{1,10,5,-1},{2,9,6,-1},{3,8,7,-1}},   // h=0
  {{0,5,12,-1},{1,4,10,-1},{2,3,11,-1},{6,7,8,9}}    // h=1
};

// ================= prep: conv+relu+combine, rec spectrum, tables =================
__global__ __launch_bounds__(256) void k_prep(const float* __restrict__ rec,
                                              const float* __restrict__ lig,
                                              const float* __restrict__ wr,
                                              const float* __restrict__ br,
                                              const float* __restrict__ wsc) {
  const int blk = blockIdx.x;
  const int tid = threadIdx.x;
  if (blk == NB) {
    // W table (y-DFT twiddles)
    for (int u = tid; u < H*WST; u += 256) {
      int y = u / WST, col = u % WST;
      float v = 0.f;
      if (col < 2*NBIN) {
        int om = col >> 1;
        int k = (om * y) % SD;
        double ang = 6.283185307179586 * (double)k / 100.0;
        v = (col & 1) ? (float)(-sin(ang)) : (float)cos(ang);
      }
      g_W[u] = v;
    }
    // inverse table: (cos, sin) for dy = 0..49, zeros for 50..63
    for (int u = tid; u < NBIN*128; u += 256) {
      int om = u >> 7, q = u & 127;
      int dy = q >> 1;
      float v = 0.f;
      if (dy <= 49) {
        int k = (om * dy) % SD;
        double ang = 6.283185307179586 * (double)k / 100.0;
        v = (q & 1) ? (float)sin(ang) : (float)cos(ang);
      }
      g_P[u] = v;
    }
    return;
  }
  const int b = blk;
  __shared__ float recf[2*H*H];
  __shared__ float tbl[SD*2];
  for (int k = tid; k < SD; k += 256) {
    double ang = 6.283185307179586 * (double)k / 100.0;
    tbl[2*k]   = (float)cos(ang);
    tbl[2*k+1] = (float)sin(ang);
  }
  const float* rimg = rec + b*H*H;
  const float* limg = lig + b*H*H;
  for (int p = tid; p < H*H; p += 256) {
    int i = p / H, j = p - (p/H)*H;
    float ar0 = br[0], ar1 = br[1], al0 = br[0], al1 = br[1];
    for (int di = 0; di < 3; ++di) {
      int ii = i + di - 1;
      if (ii < 0 || ii >= H) continue;
      for (int dj = 0; dj < 3; ++dj) {
        int jj = j + dj - 1;
        if (jj < 0 || jj >= H) continue;
        float rv = rimg[ii*H+jj], lv = limg[ii*H+jj];
        float w0 = wr[di*3 + dj], w1 = wr[9 + di*3 + dj];
        ar0 += w0*rv; ar1 += w1*rv; al0 += w0*lv; al1 += w1*lv;
      }
    }
    ar0 = fmaxf(ar0, 0.f); ar1 = fmaxf(ar1, 0.f);
    al0 = fmaxf(al0, 0.f); al1 = fmaxf(al1, 0.f);
    recf[p] = ar0; recf[H*H + p] = ar1;
    g_ligc[((b*2+0)*H + i)*H + j] = wsc[0]*al0 + wsc[1]*al1;
    g_ligc[((b*2+1)*H + i)*H + j] = wsc[2]*al0 + wsc[3]*al1;
  }
  // zero-pad A rows 50..57 (both channels)
  for (int u = tid; u < 2*8*102; u += 256) {
    int c = u / 816; int r = u % 816;
    int x = 50 + r / 102; int q = r % 102;
    g_Arec[((b*2+c)*AX + x)*102 + q] = 0.f;
  }
  __syncthreads();
  // row-DFT of rec features -> g_Arec
  for (int u = tid; u < 2*H*NBIN; u += 256) {
    int om = u % NBIN; int rest = u / NBIN; int x = rest % H; int c = rest / H;
    const float* row = recf + (c*H + x)*H;
    float sr = 0.f, si = 0.f;
    int k = 0;
    for (int y = 0; y < H; ++y) {
      float rv = row[y];
      sr += rv * tbl[2*k];
      si -= rv * tbl[2*k+1];
      k += om; if (k >= SD) k -= SD;
    }
    float* dst = g_Arec + ((b*2+c)*AX + x)*102 + 2*om;
    dst[0] = sr; dst[1] = si;
  }
}

#define P3_FMA(uu) do { \
  float Ar = ar_[(uu)&7], Ai = ai_[(uu)&7]; \
  { const int sl=(uu)&7;     cr0 += Ar*br_[sl] + Ai*bi_[sl]; ci0 += Ar*bi_[sl] - Ai*br_[sl]; } \
  { const int sl=((uu)+1)&7; cr1 += Ar*br_[sl] + Ai*bi_[sl]; ci1 += Ar*bi_[sl] - Ai*br_[sl]; } \
  { const int sl=((uu)+2)&7; cr2 += Ar*br_[sl] + Ai*bi_[sl]; ci2 += Ar*bi_[sl] - Ai*br_[sl]; } \
  { const int sl=((uu)+3)&7; cr3 += Ar*br_[sl] + Ai*bi_[sl]; ci3 += Ar*bi_[sl] - Ai*br_[sl]; } \
} while(0)

// ================= main: per (angle,batch) block =================
__global__ __launch_bounds__(256) void k_main() {
  const int bid = blockIdx.x;
  const int a = bid % NANG;
  const int b = bid / NANG;
  const int tid = threadIdx.x;

  __shared__ __align__(16) float sB[2*BROWS*BST];   // B-hat: [c][row][2*om+p]
  __shared__ __align__(16) float sRC[2*NBIN*CST];   // union: Rt then Cr|Ci
  __shared__ float sRedV[256];
  __shared__ int   sRedP[256];
  float* Rt = sRC;                    // [c][j][i], stride RTST
  float* Cr = sRC;                    // [om][lagIdx], stride CST
  float* Ci = sRC + NBIN*CST;

  // P0: zero-fill pad rows of sB
  for (int u = tid; u < 2*BROWS*BST; u += 256) {
    int row = (u / BST) % BROWS;
    if (row < PADB || row >= PADB + H) sB[u] = 0.f;
  }

  // P1: bilinear rotation of combined ligand features -> Rt (transposed)
  float angf = 0.05235987755982988f * (float)a;
  float ca = cosf(angf), sa = sinf(angf);
  const float* L0 = g_ligc + (b*2+0)*H*H;
  const float* L1 = g_ligc + (b*2+1)*H*H;
  for (int p = tid; p < H*H; p += 256) {
    int i = p / H, j = p - (p/H)*H;
    float gy = -1.f + (float)i*(2.f/49.f);
    float gx = -1.f + (float)j*(2.f/49.f);
    float x_in = ca*gx - sa*gy;
    float y_in = sa*gx + ca*gy;
    float px = (x_in + 1.f)*0.5f*49.f;
    float py = (y_in + 1.f)*0.5f*49.f;
    float fx = floorf(px), fy = floorf(py);
    int x0 = (int)fx, y0 = (int)fy;
    int x1 = x0 + 1, y1 = y0 + 1;
    float wx1 = px - fx, wx0 = 1.f - wx1;
    float wy1 = py - fy, wy0 = 1.f - wy1;
    float v0 = 0.f, v1 = 0.f;
    if (y0 >= 0 && y0 < H) {
      if (x0 >= 0 && x0 < H) { float w = wy0*wx0; int o = y0*H+x0; v0 += w*L0[o]; v1 += w*L1[o]; }
      if (x1 >= 0 && x1 < H) { float w = wy0*wx1; int o = y0*H+x1; v0 += w*L0[o]; v1 += w*L1[o]; }
    }
    if (y1 >= 0 && y1 < H) {
      if (x0 >= 0 && x0 < H) { float w = wy1*wx0; int o = y1*H+x0; v0 += w*L0[o]; v1 += w*L1[o]; }
      if (x1 >= 0 && x1 < H) { float w = wy1*wx1; int o = y1*H+x1; v0 += w*L0[o]; v1 += w*L1[o]; }
    }
    Rt[(0*H + j)*RTST + i] = v0;
    Rt[(1*H + j)*RTST + i] = v1;
  }
  __syncthreads();

  // P2: y-DFT of rotated rows -> sB. Lanes: col-group fastest (conflict-free Rt broadcast)
  if (tid < 234) {
    int c = tid / 117;
    int r = tid % 117;
    int cg = r % 9;               // fast across lanes
    int it = r / 9;               // 0..12
    int i0 = it*4;
    int col0 = (cg == 8) ? 90 : 12*cg;   // last tile overlaps (benign identical writes)
    float acc[4][12];
    #pragma unroll
    for (int p = 0; p < 4; ++p)
      #pragma unroll
      for (int q = 0; q < 12; ++q) acc[p][q] = 0.f;
    const float* rtc = Rt + c*H*RTST + i0;
    const float* wt = g_W + col0;
    #pragma unroll 2
    for (int y = 0; y < H; ++y) {
      float4 rv = *(const float4*)&rtc[y*RTST];
      float ww[12];
      #pragma unroll
      for (int q = 0; q < 6; ++q) {
        float2 w2 = *(const float2*)&wt[y*WST + 2*q];
        ww[2*q] = w2.x; ww[2*q+1] = w2.y;
      }
      float rr[4] = {rv.x, rv.y, rv.z, rv.w};
      #pragma unroll
      for (int p = 0; p < 4; ++p)
        #pragma unroll
        for (int q = 0; q < 12; ++q) acc[p][q] += rr[p]*ww[q];
    }
    float* dst = sB + c*BROWS*BST + col0;
    #pragma unroll
    for (int p = 0; p < 4; ++p) {
      int i = i0 + p;
      if (i < H) {
        #pragma unroll
        for (int q = 0; q < 6; ++q) {
          float2 o = {acc[p][2*q], acc[p][2*q+1]};
          *(float2*)&dst[(PADB+i)*BST + 2*q] = o;
        }
      }
    }
  }
  __syncthreads();

  float bestV = 3.0e38f; int bestP = 0;
  const int wid = tid >> 6, lane = tid & 63;
  const int om = (lane <= 50) ? lane : 50;
  const bool omValid = (lane <= 50);

  for (int h = 0; h < 2; ++h) {
    const int lagBase = h ? -1 : -49;

    // P3: per-bin complex correlation along x -> C[om][lag] (clamp-free steady state)
    for (int ti = 0; ti < 4; ++ti) {
      int t = g_sched[h][wid][ti];
      if (t < 0) break;
      const int d0 = lagBase + 4*t;
      const int x_lo = max(0, -(d0+3));
      const int x_hi = min(H, H - d0);
      const int ng = (x_hi - x_lo + 7) >> 3;
      float cr0=0,cr1=0,cr2=0,cr3=0, ci0=0,ci1=0,ci2=0,ci3=0;
      #pragma unroll 1
      for (int c = 0; c < 2; ++c) {
        const float* Ap = g_Arec + ((b*2+c)*AX + x_lo)*102 + 2*om;
        const float* Bp = sB + c*BROWS*BST + (PADB + x_lo + d0)*BST + 2*om;
        float br_[8], bi_[8], ar_[8], ai_[8];
        #pragma unroll
        for (int s = 0; s < 8; ++s) {
          float2 bv = *(const float2*)&Bp[s*BST];
          br_[s] = bv.x; bi_[s] = bv.y;
          float2 av = *(const float2*)&Ap[s*102];
          ar_[s] = av.x; ai_[s] = av.y;
        }
        #pragma unroll 1
        for (int g = 0; g < ng-1; ++g) {
          #pragma unroll
          for (int u = 0; u < 8; ++u) {
            P3_FMA(u);
            float2 bv = *(const float2*)&Bp[(u+8)*BST];
            br_[u] = bv.x; bi_[u] = bv.y;
            float2 av = *(const float2*)&Ap[(u+8)*102];
            ar_[u] = av.x; ai_[u] = av.y;
          }
          Bp += 8*BST; Ap += 8*102;
        }
        // final group: no A prefetch; 3 clamped B reloads for wrapped slots
        {
          const int rowcap = 56 - (x_lo + 8*(ng-1) + d0);  // >= 7; rows >= 50 are zero
          P3_FMA(0); P3_FMA(1); P3_FMA(2); P3_FMA(3); P3_FMA(4);
          #pragma unroll
          for (int s = 0; s < 3; ++s) {
            int o = min(8+s, rowcap);
            float2 bv = *(const float2*)&Bp[o*BST];
            br_[s] = bv.x; bi_[s] = bv.y;
          }
          P3_FMA(5); P3_FMA(6); P3_FMA(7);
        }
      }
      if (om == 0 || om == 50) {
        cr0*=0.5f; cr1*=0.5f; cr2*=0.5f; cr3*=0.5f;
        ci0*=0.5f; ci1*=0.5f; ci2*=0.5f; ci3*=0.5f;
      }
      if (omValid) {
        float2 a0 = {cr0, cr1}; *(float2*)&Cr[om*CST + 4*t]     = a0;
        float2 a1 = {cr2, cr3}; *(float2*)&Cr[om*CST + 4*t + 2] = a1;
        float2 a2 = {ci0, ci1}; *(float2*)&Ci[om*CST + 4*t]     = a2;
        float2 a3 = {ci2, ci3}; *(float2*)&Ci[om*CST + 4*t + 2] = a3;
      }
    }
    __syncthreads();

    // P4: inverse DFT along omega with +-dy symmetry (half the FMAs)
    {
      const int nLT = h ? 13 : 12;
      const int units = nLT * 17;
      if (tid < units) {
        int lt = tid % nLT;
        int dt = tid / nLT;         // 0..16
        int l0 = 4*lt, dy0 = 3*dt;  // dy0 0..48
        float su[4][3], sv[4][3];
        #pragma unroll
        for (int k = 0; k < 4; ++k)
          #pragma unroll
          for (int j = 0; j < 3; ++j) { su[k][j] = 0.f; sv[k][j] = 0.f; }
        const float* crp = Cr + l0;
        const float* cip = Ci + l0;
        const float* tp = g_P + 2*dy0;
        #pragma unroll 3
        for (int om2 = 0; om2 < NBIN; ++om2) {
          float2 c01 = *(const float2*)&crp[om2*CST];
          float2 c23 = *(const float2*)&crp[om2*CST + 2];
          float2 i01 = *(const float2*)&cip[om2*CST];
          float2 i23 = *(const float2*)&cip[om2*CST + 2];
          float2 t0 = *(const float2*)&tp[om2*128];
          float2 t1 = *(const float2*)&tp[om2*128 + 2];
          float2 t2 = *(const float2*)&tp[om2*128 + 4];
          float cc[4] = {c01.x, c01.y, c23.x, c23.y};
          float ii[4] = {i01.x, i01.y, i23.x, i23.y};
          float co[3] = {t0.x, t1.x, t2.x};
          float si[3] = {t0.y, t1.y, t2.y};
          #pragma unroll
          for (int k = 0; k < 4; ++k)
            #pragma unroll
            for (int j = 0; j < 3; ++j) {
              su[k][j] += cc[k]*co[j];
              sv[k][j] += ii[k]*si[j];
            }
        }
        #pragma unroll
        for (int k = 0; k < 4; ++k) {
          int lag = lagBase + l0 + k;
          if (lag <= 49) {
            #pragma unroll
            for (int j = 0; j < 3; ++j) {
              int dy = dy0 + j;
              if (dy <= 49) {
                float vp = su[k][j] - sv[k][j];   // d = 49+dy
                float vm = su[k][j] + sv[k][j];   // d = 49-dy
                int posp = (lag + 50)*SD + (50 + dy);
                int posm = (lag + 50)*SD + (50 - dy);
                if (vp < bestV || (vp == bestV && posp < bestP)) { bestV = vp; bestP = posp; }
                if (vm < bestV || (vm == bestV && posm < bestP)) { bestV = vm; bestP = posm; }
              }
            }
          }
        }
      }
    }
    __syncthreads();
  }

  // block min-reduce (lexicographic (val, pos))
  sRedV[tid] = bestV; sRedP[tid] = bestP;
  __syncthreads();
  for (int off = 128; off > 0; off >>= 1) {
    if (tid < off) {
      float v2 = sRedV[tid+off]; int p2 = sRedP[tid+off];
      if (v2 < sRedV[tid] || (v2 == sRedV[tid] && p2 < sRedP[tid])) {
        sRedV[tid] = v2; sRedP[tid] = p2;
      }
    }
    __syncthreads();
  }
  if (tid == 0) { g_resV[bid] = sRedV[0]; g_resP[bid] = sRedP[0]; }
}

// ================= final: reduce over angles, emit outputs =================
__global__ void k_final(float* __restrict__ out) {
  int b = threadIdx.x;
  if (b >= NB) return;
  float bv = 0.f; int bp = 0; int ba = 0;
  for (int a = 0; a < NANG; ++a) {
    float v = g_resV[b*NANG + a];
    if (v < bv) { bv = v; bp = g_resP[b*NANG + a]; ba = a; }
  }
  out[b] = 0.05235987755982988f * (float)ba;
  out[NB + 2*b]     = (float)(bp / SD) - 50.f;
  out[NB + 2*b + 1] = (float)(bp % SD) - 50.f;
}

extern "C" void kernel_launch(void* const* d_in, const int* in_sizes, int n_in,
                              void* d_out, int out_size, void* d_ws, size_t ws_size,
                              hipStream_t stream) {
  const float* rec = (const float*)d_in[0];
  const float* lig = (const float*)d_in[1];
  const float* wr  = (const float*)d_in[2];
  const float* br  = (const float*)d_in[3];
  const float* wsc = (const float*)d_in[4];
  (void)in_sizes; (void)n_in; (void)out_size; (void)d_ws; (void)ws_size;
  hipLaunchKernelGGL(k_prep, dim3(NB+1), dim3(256), 0, stream, rec, lig, wr, br, wsc);
  hipLaunchKernelGGL(k_main, dim3(NANG*NB), dim3(256), 0, stream);
  hipLaunchKernelGGL(k_final, dim3(1), dim3(64), 0, stream, (float*)d_out);
}